// Round 2
// baseline (323.552 us; speedup 1.0000x reference)
//
#include <hip/hip_runtime.h>

// MoE: M=4096, K=1024, E=8, N=1024, TOPK=2
// out[m] = sum_t topk_w[m,t] * ( silu(hs[m]@w1[e][:, :N]) * (hs[m]@w1[e][:, N:]) ) @ w2[e]

#define M_TOK   4096
#define K_DIM   1024
#define N_DIM   1024
#define E_NUM   8
#define NPAIR   8192            // M_TOK * TOPK
#define BM      64
#define ROWS_CAP 8704           // NPAIR + E_NUM*BM
#define NROWBLK 136             // ROWS_CAP / BM

typedef unsigned short u16;
typedef unsigned int   u32;
typedef __attribute__((ext_vector_type(8))) short bf16x8;
typedef __attribute__((ext_vector_type(4))) float f32x4;

#define GPTR(p) ((const __attribute__((address_space(1))) u32*)(const void*)(p))
#define LPTR(p) ((__attribute__((address_space(3))) u32*)(void*)(p))

__device__ __forceinline__ u16 f2bf(float f) {
  union { float f; u32 u; } v; v.f = f;
  u32 r = v.u + 0x7FFFu + ((v.u >> 16) & 1u);   // RNE
  return (u16)(r >> 16);
}
__device__ __forceinline__ float bf2f(u16 u) {
  union { u32 u; float f; } v; v.u = ((u32)u) << 16;
  return v.f;
}

// ---------------- routing: ballot-based bucket by expert, pad to BM -----------
__global__ __launch_bounds__(256) void routing_kernel(
    const int* __restrict__ topk_ids, int* __restrict__ pair_token,
    int* __restrict__ pos_of, int* __restrict__ block_expert) {
  __shared__ int cnt[E_NUM], off[E_NUM], cur[E_NUM], pad[E_NUM];
  const int t = threadIdx.x, wave = t >> 6, lane = t & 63;
  if (t < E_NUM) cnt[t] = 0;
  __syncthreads();
  // count via per-wave ballots (uniform across lanes; lane 0 commits)
  int wcnt[E_NUM] = {0, 0, 0, 0, 0, 0, 0, 0};
  for (int c = wave; c < NPAIR / 64; c += 4) {
    int e = topk_ids[c * 64 + lane] & 7;
#pragma unroll
    for (int ee = 0; ee < E_NUM; ++ee)
      wcnt[ee] += (int)__popcll(__ballot(e == ee));
  }
  if (lane == 0) {
#pragma unroll
    for (int ee = 0; ee < E_NUM; ++ee) atomicAdd(&cnt[ee], wcnt[ee]);
  }
  __syncthreads();
  if (t == 0) {
    int run = 0, blk = 0;
    for (int e = 0; e < E_NUM; ++e) {
      off[e] = run; cur[e] = run;
      int padded = ((cnt[e] + BM - 1) / BM) * BM;
      pad[e] = padded;
      for (int b = 0; b < padded / BM; ++b) block_expert[blk++] = e;
      run += padded;
    }
    for (; blk < NROWBLK; ++blk) block_expert[blk] = -1;
  }
  __syncthreads();
  // pad rows point at token 0 (computed, never gathered)
  for (int e = 0; e < E_NUM; ++e) {
    int s = off[e] + cnt[e], epos = off[e] + pad[e];
    for (int r = s + t; r < epos; r += 256) pair_token[r] = 0;
  }
  // rank-based position assignment: one LDS atomic per wave per expert per chunk
  for (int c = wave; c < NPAIR / 64; c += 4) {
    int p = c * 64 + lane;
    int e = topk_ids[p] & 7;
#pragma unroll
    for (int ee = 0; ee < E_NUM; ++ee) {
      unsigned long long m = __ballot(e == ee);
      if (e == ee) {
        int rank = (int)__popcll(m & ((1ull << lane) - 1ull));
        int nset = (int)__popcll(m);
        int leader = (int)__ffsll((unsigned long long)m) - 1;
        int base = 0;
        if (lane == leader) base = atomicAdd(&cur[ee], nset);
        base = __shfl(base, leader);
        int pos = base + rank;
        pair_token[pos] = p >> 1;
        pos_of[p] = pos;
      }
    }
  }
}

// ---------------- fp32 -> bf16 flat convert (hidden states) -------------------
__global__ __launch_bounds__(256) void convert_kernel(
    const float* __restrict__ in, u16* __restrict__ out) {
  int i = blockIdx.x * 256 + threadIdx.x;
  float4 v = ((const float4*)in)[i];
  ushort4 o;
  o.x = f2bf(v.x); o.y = f2bf(v.y); o.z = f2bf(v.z); o.w = f2bf(v.w);
  ((ushort4*)out)[i] = o;
}

// ---------------- fp32 (R,Cc) -> bf16 (Cc,R) transpose per matrix -------------
__global__ __launch_bounds__(256) void transpose_convert(
    const float* __restrict__ in, u16* __restrict__ out, int R, int Cc) {
  __shared__ float lds[64][65];
  const float* src = in + (size_t)blockIdx.z * R * Cc;
  u16* dst = out + (size_t)blockIdx.z * R * Cc;
  int r0 = blockIdx.x * 64, c0 = blockIdx.y * 64;
  int t = threadIdx.x;
#pragma unroll
  for (int it = 0; it < 16; ++it) {
    int lin = it * 256 + t;
    int rr = lin >> 6, cc = lin & 63;
    lds[cc][rr] = src[(size_t)(r0 + rr) * Cc + c0 + cc];
  }
  __syncthreads();
#pragma unroll
  for (int it = 0; it < 8; ++it) {
    int lin = it * 512 + t * 2;
    int cc = lin >> 6, rr = lin & 63;
    ushort2 o;
    o.x = f2bf(lds[cc][rr]);
    o.y = f2bf(lds[cc][rr + 1]);
    *(ushort2*)&dst[(size_t)(c0 + cc) * R + r0 + rr] = o;
  }
}

// ---------------- grouped GEMM, 64x128 tile, NB B-matrices --------------------
// NB=2: fused gate|up GEMM1 -> h = silu(gate)*up.  NB=1: plain GEMM2 -> y.
// LDS rows hold 64 k-elems as 8 16B chunks, position p stores source chunk
// p ^ (row&7) (XOR swizzle; staging lane mapping keeps global_load_lds's
// wave-uniform-base + lane*16 contiguity).
template <bool GATHER, int NB>
__global__ __launch_bounds__(256, NB == 2 ? 3 : 4) void gemm64(
    const u16* __restrict__ A, const u16* __restrict__ Bt, u16* __restrict__ Out,
    const int* __restrict__ pair_token, const int* __restrict__ block_expert) {
  const int e = block_expert[blockIdx.x];
  if (e < 0) return;
  __shared__ __align__(16) u16 As[64 * 64];
  __shared__ __align__(16) u16 Bs[NB * 128 * 64];
  const int tid = threadIdx.x;
  const int wave = tid >> 6;
  const int lane = tid & 63;
  const int srow = wave * 8 + (lane >> 3);   // staging row (32-row shot)
  const int kc = ((lane & 7) ^ (srow & 7)) << 3;  // swizzled src chunk (elems)

  const u16* ap[2];
#pragma unroll
  for (int is = 0; is < 2; ++is) {
    int rt = is * 32 + srow;
    int grow = blockIdx.x * BM + rt;
    int arow = GATHER ? pair_token[grow] : grow;
    ap[is] = A + (size_t)arow * K_DIM + kc;
  }
  const u16* bp[NB][4];
  const u16* base_e = Bt + (size_t)e * (NB * N_DIM) * K_DIM;
#pragma unroll
  for (int nb = 0; nb < NB; ++nb)
#pragma unroll
    for (int is = 0; is < 4; ++is) {
      int rt = is * 32 + srow;
      int n = nb * N_DIM + blockIdx.y * 128 + rt;
      bp[nb][is] = base_e + (size_t)n * K_DIM + kc;
    }
  u16* alds = As + wave * 512;
  u16* blds = Bs + wave * 512;

  f32x4 acc[NB][4][2];
#pragma unroll
  for (int nb = 0; nb < NB; ++nb)
#pragma unroll
    for (int i = 0; i < 4; ++i)
#pragma unroll
      for (int j = 0; j < 2; ++j) acc[nb][i][j] = f32x4{0.f, 0.f, 0.f, 0.f};

  for (int k0 = 0; k0 < K_DIM; k0 += 64) {
#pragma unroll
    for (int is = 0; is < 2; ++is)
      __builtin_amdgcn_global_load_lds(GPTR(ap[is] + k0), LPTR(alds + is * 2048), 16, 0, 0);
#pragma unroll
    for (int nb = 0; nb < NB; ++nb)
#pragma unroll
      for (int is = 0; is < 4; ++is)
        __builtin_amdgcn_global_load_lds(GPTR(bp[nb][is] + k0), LPTR(blds + nb * 8192 + is * 2048), 16, 0, 0);
    __syncthreads();
#pragma unroll
    for (int ks = 0; ks < 2; ++ks) {
      const int cq = ks * 4 + (lane >> 4);
      bf16x8 af[4], bfr[NB][2];
#pragma unroll
      for (int i = 0; i < 4; ++i) {
        int row = i * 16 + (lane & 15);
        af[i] = *(const bf16x8*)&As[row * 64 + ((cq ^ (row & 7)) << 3)];
      }
#pragma unroll
      for (int nb = 0; nb < NB; ++nb)
#pragma unroll
        for (int j = 0; j < 2; ++j) {
          int n = wave * 32 + j * 16 + (lane & 15);
          bfr[nb][j] = *(const bf16x8*)&Bs[nb * 8192 + n * 64 + ((cq ^ (n & 7)) << 3)];
        }
#pragma unroll
      for (int nb = 0; nb < NB; ++nb)
#pragma unroll
        for (int i = 0; i < 4; ++i)
#pragma unroll
          for (int j = 0; j < 2; ++j)
            acc[nb][i][j] = __builtin_amdgcn_mfma_f32_16x16x32_bf16(af[i], bfr[nb][j], acc[nb][i][j], 0, 0, 0);
    }
    __syncthreads();
  }

  // epilogue: C/D layout col=lane&15, row=(lane>>4)*4+reg (m89/m91-verified)
  const size_t rbase = (size_t)blockIdx.x * BM + ((lane >> 4) * 4);
  const int cbase = blockIdx.y * 128 + wave * 32 + (lane & 15);
#pragma unroll
  for (int i = 0; i < 4; ++i)
#pragma unroll
    for (int j = 0; j < 2; ++j)
#pragma unroll
      for (int r = 0; r < 4; ++r) {
        float v;
        if (NB == 2) {
          float g = acc[0][i][j][r], u = acc[1][i][j][r];
          v = g * u / (1.f + __expf(-g));
        } else {
          v = acc[0][i][j][r];
        }
        Out[(rbase + i * 16 + r) * N_DIM + cbase + j * 16] = f2bf(v);
      }
}

// ---------------- gather: out[m] = w0*y[pos0] + w1*y[pos1] --------------------
__global__ __launch_bounds__(256) void gather_kernel(
    const u16* __restrict__ y, const float* __restrict__ tw,
    const int* __restrict__ pos_of, float* __restrict__ out) {
  int m = blockIdx.x;
  int k = threadIdx.x * 4;
  int p0 = pos_of[m * 2 + 0], p1 = pos_of[m * 2 + 1];
  float w0 = tw[m * 2 + 0], w1 = tw[m * 2 + 1];
  ushort4 y0 = *(const ushort4*)&y[(size_t)p0 * 1024 + k];
  ushort4 y1 = *(const ushort4*)&y[(size_t)p1 * 1024 + k];
  float4 o;
  o.x = w0 * bf2f(y0.x) + w1 * bf2f(y1.x);
  o.y = w0 * bf2f(y0.y) + w1 * bf2f(y1.y);
  o.z = w0 * bf2f(y0.z) + w1 * bf2f(y1.z);
  o.w = w0 * bf2f(y0.w) + w1 * bf2f(y1.w);
  *(float4*)&out[(size_t)m * 1024 + k] = o;
}

extern "C" void kernel_launch(void* const* d_in, const int* in_sizes, int n_in,
                              void* d_out, int out_size, void* d_ws, size_t ws_size,
                              hipStream_t stream) {
  const float* hs = (const float*)d_in[0];
  const float* w1 = (const float*)d_in[1];
  const float* w2 = (const float*)d_in[2];
  const float* tw = (const float*)d_in[3];
  const int* tids = (const int*)d_in[4];
  float* out = (float*)d_out;

  char* ws = (char*)d_ws;
  u16* hsb = (u16*)(ws);                                 //  8 MB  (M,K) bf16
  u16* w1t = (u16*)(ws + (size_t)(8u << 20));            // 32 MB  (E,2N,K) bf16
  u16* w2t = (u16*)(ws + (size_t)(40u << 20));           // 16 MB  (E,K,N)  bf16
  u16* h   = (u16*)(ws + (size_t)(56u << 20));           // 17 MB  (ROWS_CAP,N)
  u16* y   = (u16*)(ws + (size_t)(76u << 20));           // 17 MB  (ROWS_CAP,K)
  int* pair_token   = (int*)(ws + (size_t)(96u << 20));
  int* pos_of       = (int*)(ws + (size_t)(96u << 20) + 64 * 1024);
  int* block_expert = (int*)(ws + (size_t)(96u << 20) + 128 * 1024);

  routing_kernel<<<1, 256, 0, stream>>>(tids, pair_token, pos_of, block_expert);
  convert_kernel<<<4096, 256, 0, stream>>>(hs, hsb);
  transpose_convert<<<dim3(16, 32, E_NUM), 256, 0, stream>>>(w1, w1t, 1024, 2048);
  transpose_convert<<<dim3(16, 16, E_NUM), 256, 0, stream>>>(w2, w2t, 1024, 1024);
  gemm64<true, 2><<<dim3(NROWBLK, 8), 256, 0, stream>>>(hsb, w1t, h, pair_token, block_expert);
  gemm64<false, 1><<<dim3(NROWBLK, 8), 256, 0, stream>>>(h, w2t, y, pair_token, block_expert);
  gather_kernel<<<4096, 256, 0, stream>>>(y, tw, pos_of, out);
}

// Round 3
// 264.039 us; speedup vs baseline: 1.2254x; 1.2254x over previous
//
#include <hip/hip_runtime.h>

// MoE: M=4096, K=1024, E=8, N=1024, TOPK=2
// out[m] = sum_t topk_w[m,t] * ( silu(hs[m]@w1[e][:, :N]) * (hs[m]@w1[e][:, N:]) ) @ w2[e]

#define M_TOK   4096
#define K_DIM   1024
#define N_DIM   1024
#define E_NUM   8
#define NPAIR   8192            // M_TOK * TOPK
#define BM      64
#define ROWS_CAP 8704           // NPAIR + E_NUM*BM
#define NROWBLK 136             // ROWS_CAP / BM
#define HBLK    32              // routing blocks (NPAIR / 256)

typedef unsigned short u16;
typedef unsigned int   u32;
typedef __attribute__((ext_vector_type(8))) short bf16x8;
typedef __attribute__((ext_vector_type(4))) float f32x4;

#define GPTR(p) ((const __attribute__((address_space(1))) u32*)(const void*)(p))
#define LPTR(p) ((__attribute__((address_space(3))) u32*)(void*)(p))

__device__ __forceinline__ u16 f2bf(float f) {
  union { float f; u32 u; } v; v.f = f;
  u32 r = v.u + 0x7FFFu + ((v.u >> 16) & 1u);   // RNE
  return (u16)(r >> 16);
}
__device__ __forceinline__ float bf2f(u16 u) {
  union { u32 u; float f; } v; v.u = ((u32)u) << 16;
  return v.f;
}

// ---------------- routing stage 1: per-block expert histogram (no atomics) ----
__global__ __launch_bounds__(256) void hist_kernel(
    const int* __restrict__ topk_ids, int* __restrict__ blockhist) {
  __shared__ int wcnt[4][E_NUM];
  const int t = threadIdx.x, wave = t >> 6, lane = t & 63;
  int e = topk_ids[blockIdx.x * 256 + t] & 7;
#pragma unroll
  for (int ee = 0; ee < E_NUM; ++ee) {
    unsigned long long m = __ballot(e == ee);
    if (lane == ee) wcnt[wave][ee] = (int)__popcll(m);
  }
  __syncthreads();
  if (t < E_NUM) {
    int s = wcnt[0][t] + wcnt[1][t] + wcnt[2][t] + wcnt[3][t];
    blockhist[blockIdx.x * E_NUM + t] = s;
  }
}

// ---------------- routing stage 2: scan, offsets, block_expert, pad fill ------
__global__ __launch_bounds__(256) void scan_kernel(
    const int* __restrict__ blockhist, int* __restrict__ baseoff,
    int* __restrict__ pair_token, int* __restrict__ block_expert) {
  __shared__ int cnt[E_NUM], off[E_NUM], pad[E_NUM];
  const int t = threadIdx.x;
  if (t < E_NUM) {
    int run = 0;
    for (int b = 0; b < HBLK; ++b) {
      baseoff[b * E_NUM + t] = run;          // exclusive prefix within expert t
      run += blockhist[b * E_NUM + t];
    }
    cnt[t] = run;
  }
  __syncthreads();
  if (t == 0) {
    int run = 0, blk = 0;
    for (int e = 0; e < E_NUM; ++e) {
      off[e] = run;
      int padded = ((cnt[e] + BM - 1) / BM) * BM;
      pad[e] = padded;
      for (int b = 0; b < padded / BM; ++b) block_expert[blk++] = e;
      run += padded;
    }
    for (; blk < NROWBLK; ++blk) block_expert[blk] = -1;
  }
  __syncthreads();
  // shift per-block bases by expert segment start
  for (int i = t; i < HBLK * E_NUM; i += 256) baseoff[i] += off[i & 7];
  // pad rows point at token 0 (computed, never gathered)
  for (int e = 0; e < E_NUM; ++e) {
    int s = off[e] + cnt[e], epos = off[e] + pad[e];
    for (int r = s + t; r < epos; r += 256) pair_token[r] = 0;
  }
}

// ---------------- routing stage 3: deterministic position assignment ----------
__global__ __launch_bounds__(256) void assign_kernel(
    const int* __restrict__ topk_ids, const int* __restrict__ baseoff,
    int* __restrict__ pair_token, int* __restrict__ pos_of) {
  __shared__ int wcnt[4][E_NUM], wbase[4][E_NUM];
  const int t = threadIdx.x, wave = t >> 6, lane = t & 63;
  const int p = blockIdx.x * 256 + t;
  const int e = topk_ids[p] & 7;
  int rank = 0;
#pragma unroll
  for (int ee = 0; ee < E_NUM; ++ee) {
    unsigned long long m = __ballot(e == ee);
    if (e == ee) rank = (int)__popcll(m & ((1ull << lane) - 1ull));
    if (lane == ee) wcnt[wave][ee] = (int)__popcll(m);
  }
  __syncthreads();
  if (t < E_NUM) {
    int run = baseoff[blockIdx.x * E_NUM + t];
    for (int w = 0; w < 4; ++w) { wbase[w][t] = run; run += wcnt[w][t]; }
  }
  __syncthreads();
  int pos = wbase[wave][e] + rank;
  pair_token[pos] = p >> 1;
  pos_of[p] = pos;
}

// ---------------- fp32 -> bf16 flat convert (hidden states) -------------------
__global__ __launch_bounds__(256) void convert_kernel(
    const float* __restrict__ in, u16* __restrict__ out) {
  int i = blockIdx.x * 256 + threadIdx.x;
  float4 v = ((const float4*)in)[i];
  ushort4 o;
  o.x = f2bf(v.x); o.y = f2bf(v.y); o.z = f2bf(v.z); o.w = f2bf(v.w);
  ((ushort4*)out)[i] = o;
}

// ---------------- fp32 (R,Cc) -> bf16 (Cc,R) transpose per matrix -------------
__global__ __launch_bounds__(256) void transpose_convert(
    const float* __restrict__ in, u16* __restrict__ out, int R, int Cc) {
  __shared__ float lds[64][65];
  const float* src = in + (size_t)blockIdx.z * R * Cc;
  u16* dst = out + (size_t)blockIdx.z * R * Cc;
  int r0 = blockIdx.x * 64, c0 = blockIdx.y * 64;
  int t = threadIdx.x;
#pragma unroll
  for (int it = 0; it < 16; ++it) {
    int lin = it * 256 + t;
    int rr = lin >> 6, cc = lin & 63;
    lds[cc][rr] = src[(size_t)(r0 + rr) * Cc + c0 + cc];
  }
  __syncthreads();
#pragma unroll
  for (int it = 0; it < 8; ++it) {
    int lin = it * 512 + t * 2;
    int cc = lin >> 6, rr = lin & 63;
    ushort2 o;
    o.x = f2bf(lds[cc][rr]);
    o.y = f2bf(lds[cc][rr + 1]);
    *(ushort2*)&dst[(size_t)(c0 + cc) * R + r0 + rr] = o;
  }
}

// ---------------- grouped GEMM, 64x128 tile, NB B-matrices --------------------
// NB=2: fused gate|up GEMM1 -> h = silu(gate)*up.  NB=1: plain GEMM2 -> y.
template <bool GATHER, int NB>
__global__ __launch_bounds__(256, NB == 2 ? 3 : 4) void gemm64(
    const u16* __restrict__ A, const u16* __restrict__ Bt, u16* __restrict__ Out,
    const int* __restrict__ pair_token, const int* __restrict__ block_expert) {
  const int e = block_expert[blockIdx.x];
  if (e < 0) return;
  __shared__ __align__(16) u16 As[64 * 64];
  __shared__ __align__(16) u16 Bs[NB * 128 * 64];
  const int tid = threadIdx.x;
  const int wave = tid >> 6;
  const int lane = tid & 63;
  const int srow = wave * 8 + (lane >> 3);   // staging row (32-row shot)
  const int kc = ((lane & 7) ^ (srow & 7)) << 3;  // swizzled src chunk (elems)

  const u16* ap[2];
#pragma unroll
  for (int is = 0; is < 2; ++is) {
    int rt = is * 32 + srow;
    int grow = blockIdx.x * BM + rt;
    int arow = GATHER ? pair_token[grow] : grow;
    ap[is] = A + (size_t)arow * K_DIM + kc;
  }
  const u16* bp[NB][4];
  const u16* base_e = Bt + (size_t)e * (NB * N_DIM) * K_DIM;
#pragma unroll
  for (int nb = 0; nb < NB; ++nb)
#pragma unroll
    for (int is = 0; is < 4; ++is) {
      int rt = is * 32 + srow;
      int n = nb * N_DIM + blockIdx.y * 128 + rt;
      bp[nb][is] = base_e + (size_t)n * K_DIM + kc;
    }
  u16* alds = As + wave * 512;
  u16* blds = Bs + wave * 512;

  f32x4 acc[NB][4][2];
#pragma unroll
  for (int nb = 0; nb < NB; ++nb)
#pragma unroll
    for (int i = 0; i < 4; ++i)
#pragma unroll
      for (int j = 0; j < 2; ++j) acc[nb][i][j] = f32x4{0.f, 0.f, 0.f, 0.f};

  for (int k0 = 0; k0 < K_DIM; k0 += 64) {
#pragma unroll
    for (int is = 0; is < 2; ++is)
      __builtin_amdgcn_global_load_lds(GPTR(ap[is] + k0), LPTR(alds + is * 2048), 16, 0, 0);
#pragma unroll
    for (int nb = 0; nb < NB; ++nb)
#pragma unroll
      for (int is = 0; is < 4; ++is)
        __builtin_amdgcn_global_load_lds(GPTR(bp[nb][is] + k0), LPTR(blds + nb * 8192 + is * 2048), 16, 0, 0);
    __syncthreads();
#pragma unroll
    for (int ks = 0; ks < 2; ++ks) {
      const int cq = ks * 4 + (lane >> 4);
      bf16x8 af[4], bfr[NB][2];
#pragma unroll
      for (int i = 0; i < 4; ++i) {
        int row = i * 16 + (lane & 15);
        af[i] = *(const bf16x8*)&As[row * 64 + ((cq ^ (row & 7)) << 3)];
      }
#pragma unroll
      for (int nb = 0; nb < NB; ++nb)
#pragma unroll
        for (int j = 0; j < 2; ++j) {
          int n = wave * 32 + j * 16 + (lane & 15);
          bfr[nb][j] = *(const bf16x8*)&Bs[nb * 8192 + n * 64 + ((cq ^ (n & 7)) << 3)];
        }
#pragma unroll
      for (int nb = 0; nb < NB; ++nb)
#pragma unroll
        for (int i = 0; i < 4; ++i)
#pragma unroll
          for (int j = 0; j < 2; ++j)
            acc[nb][i][j] = __builtin_amdgcn_mfma_f32_16x16x32_bf16(af[i], bfr[nb][j], acc[nb][i][j], 0, 0, 0);
    }
    __syncthreads();
  }

  // epilogue: C/D layout col=lane&15, row=(lane>>4)*4+reg (m89/m91-verified)
  const size_t rbase = (size_t)blockIdx.x * BM + ((lane >> 4) * 4);
  const int cbase = blockIdx.y * 128 + wave * 32 + (lane & 15);
#pragma unroll
  for (int i = 0; i < 4; ++i)
#pragma unroll
    for (int j = 0; j < 2; ++j)
#pragma unroll
      for (int r = 0; r < 4; ++r) {
        float v;
        if (NB == 2) {
          float g = acc[0][i][j][r], u = acc[1][i][j][r];
          v = g * u / (1.f + __expf(-g));
        } else {
          v = acc[0][i][j][r];
        }
        Out[(rbase + i * 16 + r) * N_DIM + cbase + j * 16] = f2bf(v);
      }
}

// ---------------- gather: out[m] = w0*y[pos0] + w1*y[pos1] --------------------
__global__ __launch_bounds__(256) void gather_kernel(
    const u16* __restrict__ y, const float* __restrict__ tw,
    const int* __restrict__ pos_of, float* __restrict__ out) {
  int m = blockIdx.x;
  int k = threadIdx.x * 4;
  int p0 = pos_of[m * 2 + 0], p1 = pos_of[m * 2 + 1];
  float w0 = tw[m * 2 + 0], w1 = tw[m * 2 + 1];
  ushort4 y0 = *(const ushort4*)&y[(size_t)p0 * 1024 + k];
  ushort4 y1 = *(const ushort4*)&y[(size_t)p1 * 1024 + k];
  float4 o;
  o.x = w0 * bf2f(y0.x) + w1 * bf2f(y1.x);
  o.y = w0 * bf2f(y0.y) + w1 * bf2f(y1.y);
  o.z = w0 * bf2f(y0.z) + w1 * bf2f(y1.z);
  o.w = w0 * bf2f(y0.w) + w1 * bf2f(y1.w);
  *(float4*)&out[(size_t)m * 1024 + k] = o;
}

extern "C" void kernel_launch(void* const* d_in, const int* in_sizes, int n_in,
                              void* d_out, int out_size, void* d_ws, size_t ws_size,
                              hipStream_t stream) {
  const float* hs = (const float*)d_in[0];
  const float* w1 = (const float*)d_in[1];
  const float* w2 = (const float*)d_in[2];
  const float* tw = (const float*)d_in[3];
  const int* tids = (const int*)d_in[4];
  float* out = (float*)d_out;

  char* ws = (char*)d_ws;
  u16* hsb = (u16*)(ws);                                 //  8 MB  (M,K) bf16
  u16* w1t = (u16*)(ws + (size_t)(8u << 20));            // 32 MB  (E,2N,K) bf16
  u16* w2t = (u16*)(ws + (size_t)(40u << 20));           // 16 MB  (E,K,N)  bf16
  u16* h   = (u16*)(ws + (size_t)(56u << 20));           // 17 MB  (ROWS_CAP,N)
  u16* y   = (u16*)(ws + (size_t)(76u << 20));           // 17 MB  (ROWS_CAP,K)
  int* pair_token   = (int*)(ws + (size_t)(96u << 20));
  int* pos_of       = (int*)(ws + (size_t)(96u << 20) + 64 * 1024);
  int* block_expert = (int*)(ws + (size_t)(96u << 20) + 128 * 1024);
  int* blockhist    = (int*)(ws + (size_t)(96u << 20) + 192 * 1024);  // 32*8 ints
  int* baseoff      = (int*)(ws + (size_t)(96u << 20) + 256 * 1024);  // 32*8 ints

  hist_kernel<<<HBLK, 256, 0, stream>>>(tids, blockhist);
  scan_kernel<<<1, 256, 0, stream>>>(blockhist, baseoff, pair_token, block_expert);
  assign_kernel<<<HBLK, 256, 0, stream>>>(tids, baseoff, pair_token, pos_of);
  convert_kernel<<<4096, 256, 0, stream>>>(hs, hsb);
  transpose_convert<<<dim3(16, 32, E_NUM), 256, 0, stream>>>(w1, w1t, 1024, 2048);
  transpose_convert<<<dim3(16, 16, E_NUM), 256, 0, stream>>>(w2, w2t, 1024, 1024);
  gemm64<true, 2><<<dim3(NROWBLK, 8), 256, 0, stream>>>(hsb, w1t, h, pair_token, block_expert);
  gemm64<false, 1><<<dim3(NROWBLK, 8), 256, 0, stream>>>(h, w2t, y, pair_token, block_expert);
  gather_kernel<<<4096, 256, 0, stream>>>(y, tw, pos_of, out);
}